// Round 12
// baseline (621.074 us; speedup 1.0000x reference)
//
#include <hip/hip_runtime.h>
#include <hip/hip_bf16.h>

#define HDIM 128

typedef __attribute__((ext_vector_type(8))) short bf16x8;
typedef __attribute__((ext_vector_type(4))) float f32x4;
typedef __attribute__((ext_vector_type(4))) _Float16 f16x4;

__device__ __forceinline__ unsigned short bf16_rne(float x) {
    unsigned int u = __float_as_uint(x);
    unsigned int r = u + 0x7FFFu + ((u >> 16) & 1u);
    return (unsigned short)(r >> 16);
}

// ---------------- CSR build ----------------

__global__ __launch_bounds__(256) void hist_kernel(const int* __restrict__ ei, int E,
                                                   int* __restrict__ deg) {
    int e = blockIdx.x * 256 + threadIdx.x;
    if (e < E) atomicAdd(&deg[ei[E + e]], 1);  // dst = ei[1][e]
}

__global__ __launch_bounds__(256) void scan1_kernel(const int* __restrict__ deg,
                                                    int* __restrict__ rowp,
                                                    int* __restrict__ bsum, int N) {
    __shared__ int s[256];
    int t = threadIdx.x;
    int i = blockIdx.x * 256 + t;
    int v = (i < N) ? deg[i] : 0;
    s[t] = v; __syncthreads();
    for (int off = 1; off < 256; off <<= 1) {
        int x = (t >= off) ? s[t - off] : 0;
        __syncthreads();
        s[t] += x;
        __syncthreads();
    }
    if (i < N) rowp[i] = s[t] - v;           // local exclusive
    if (t == 255) bsum[blockIdx.x] = s[255]; // block total
}

__global__ __launch_bounds__(256) void scan2_kernel(int* __restrict__ bsum, int NB) {
    __shared__ int s[256];
    int t = threadIdx.x;
    int v = (t < NB) ? bsum[t] : 0;
    s[t] = v; __syncthreads();
    for (int off = 1; off < 256; off <<= 1) {
        int x = (t >= off) ? s[t - off] : 0;
        __syncthreads();
        s[t] += x;
        __syncthreads();
    }
    if (t < NB) bsum[t] = s[t] - v;          // exclusive block offsets
}

__global__ __launch_bounds__(256) void scan3_kernel(int* __restrict__ rowp,
                                                    const int* __restrict__ bsum,
                                                    int* __restrict__ cur, int N, int E) {
    int i = blockIdx.x * 256 + threadIdx.x;
    if (i < N) {
        int r = rowp[i] + bsum[blockIdx.x];
        rowp[i] = r;
        cur[i] = r;
    }
    if (i == 0) rowp[N] = E;
}

template <typename IT>
__global__ __launch_bounds__(256) void scatter_kernel(const int* __restrict__ ei, int E,
                                                      int* __restrict__ cur,
                                                      IT* __restrict__ srcs) {
    int e = blockIdx.x * 256 + threadIdx.x;
    if (e < E) {
        int d = ei[E + e];
        int p = atomicAdd(&cur[d], 1);
        srcs[p] = (IT)ei[e];  // src = ei[0][e]
    }
}

// ---------------- W pre-pack into MFMA B-fragment order, bf16 hi/lo ----------------

__global__ __launch_bounds__(256) void pack_w_kernel(const float* __restrict__ w0a,
                                                     const float* __restrict__ w0b,
                                                     const float* __restrict__ wma,
                                                     const float* __restrict__ wmb,
                                                     short* __restrict__ wpack) {
    int idx = blockIdx.x * 256 + threadIdx.x;
    if (idx >= 10 * 16384) return;
    int mat = idx >> 14;           // 0..9
    int rem = idx & 16383;
    int i = rem & 7;
    int lane = (rem >> 3) & 63;
    int kc = (rem >> 9) & 3;
    int ct = rem >> 11;
    const float* W = (mat == 0) ? w0a
                   : (mat == 1) ? w0b
                   : (mat < 6)  ? (wma + (size_t)(mat - 2) * 16384)
                                : (wmb + (size_t)(mat - 6) * 16384);
    int k = kc * 32 + (lane >> 4) * 8 + i;
    int col = ct * 16 + (lane & 15);
    float x = W[k * 128 + col];
    unsigned short hb = bf16_rne(x);
    float hf = __uint_as_float(((unsigned int)hb) << 16);
    unsigned short lb = bf16_rne(x - hf);
    wpack[(size_t)mat * 32768 + rem] = (short)hb;
    wpack[(size_t)mat * 32768 + 16384 + rem] = (short)lb;
}

// ---------------- aggregation: out[i] = h[i] + sum_{j->i} h[j] ----------------
// Structural wall (~59us): each XCD L2 must stream all of h (random gather).

template <typename IT>
__global__ __launch_bounds__(256) void agg_kernel(const float* __restrict__ h,
                                                  const int* __restrict__ rowp,
                                                  const IT* __restrict__ srcs,
                                                  float* __restrict__ out, int N) {
    const int tid  = threadIdx.x;
    const int lane = tid & 63;
    const int half = lane >> 5;
    const int l    = lane & 31;
    const int node = blockIdx.x * 8 + ((tid >> 6) << 1) + half;
    const bool nv  = node < N;
    const int nc   = nv ? node : 0;

    const float4* h4 = (const float4*)h;
    int beg = rowp[nc];
    int end = nv ? rowp[nc + 1] : beg;
    int em1 = max(end - 1, 0);

    const float4 z = {0.f, 0.f, 0.f, 0.f};
    float4 a0 = nv ? h4[(size_t)nc * 32 + l] : z;
    float4 a1 = z, a2 = z, a3 = z, a4 = z, a5 = z, a6 = z, a7 = z;

    for (int q = beg; q < end; q += 8) {
        int c0 = min(q + 0, em1);
        int c1 = min(q + 1, em1);
        int c2 = min(q + 2, em1);
        int c3 = min(q + 3, em1);
        int c4 = min(q + 4, em1);
        int c5 = min(q + 5, em1);
        int c6 = min(q + 6, em1);
        int c7 = min(q + 7, em1);
        int s0 = (int)srcs[c0];
        int s1 = (int)srcs[c1];
        int s2 = (int)srcs[c2];
        int s3 = (int)srcs[c3];
        int s4 = (int)srcs[c4];
        int s5 = (int)srcs[c5];
        int s6 = (int)srcs[c6];
        int s7 = (int)srcs[c7];
        float4 v0 = h4[(size_t)s0 * 32 + l];
        float4 v1 = h4[(size_t)s1 * 32 + l];
        float4 v2 = h4[(size_t)s2 * 32 + l];
        float4 v3 = h4[(size_t)s3 * 32 + l];
        float4 v4 = h4[(size_t)s4 * 32 + l];
        float4 v5 = h4[(size_t)s5 * 32 + l];
        float4 v6 = h4[(size_t)s6 * 32 + l];
        float4 v7 = h4[(size_t)s7 * 32 + l];
        float m0 = (q + 0 < end) ? 1.f : 0.f;
        float m1 = (q + 1 < end) ? 1.f : 0.f;
        float m2 = (q + 2 < end) ? 1.f : 0.f;
        float m3 = (q + 3 < end) ? 1.f : 0.f;
        float m4 = (q + 4 < end) ? 1.f : 0.f;
        float m5 = (q + 5 < end) ? 1.f : 0.f;
        float m6 = (q + 6 < end) ? 1.f : 0.f;
        float m7 = (q + 7 < end) ? 1.f : 0.f;
        a0.x = fmaf(v0.x, m0, a0.x); a0.y = fmaf(v0.y, m0, a0.y);
        a0.z = fmaf(v0.z, m0, a0.z); a0.w = fmaf(v0.w, m0, a0.w);
        a1.x = fmaf(v1.x, m1, a1.x); a1.y = fmaf(v1.y, m1, a1.y);
        a1.z = fmaf(v1.z, m1, a1.z); a1.w = fmaf(v1.w, m1, a1.w);
        a2.x = fmaf(v2.x, m2, a2.x); a2.y = fmaf(v2.y, m2, a2.y);
        a2.z = fmaf(v2.z, m2, a2.z); a2.w = fmaf(v2.w, m2, a2.w);
        a3.x = fmaf(v3.x, m3, a3.x); a3.y = fmaf(v3.y, m3, a3.y);
        a3.z = fmaf(v3.z, m3, a3.z); a3.w = fmaf(v3.w, m3, a3.w);
        a4.x = fmaf(v4.x, m4, a4.x); a4.y = fmaf(v4.y, m4, a4.y);
        a4.z = fmaf(v4.z, m4, a4.z); a4.w = fmaf(v4.w, m4, a4.w);
        a5.x = fmaf(v5.x, m5, a5.x); a5.y = fmaf(v5.y, m5, a5.y);
        a5.z = fmaf(v5.z, m5, a5.z); a5.w = fmaf(v5.w, m5, a5.w);
        a6.x = fmaf(v6.x, m6, a6.x); a6.y = fmaf(v6.y, m6, a6.y);
        a6.z = fmaf(v6.z, m6, a6.z); a6.w = fmaf(v6.w, m6, a6.w);
        a7.x = fmaf(v7.x, m7, a7.x); a7.y = fmaf(v7.y, m7, a7.y);
        a7.z = fmaf(v7.z, m7, a7.z); a7.w = fmaf(v7.w, m7, a7.w);
    }

    a0.x = ((a0.x + a1.x) + (a2.x + a3.x)) + ((a4.x + a5.x) + (a6.x + a7.x));
    a0.y = ((a0.y + a1.y) + (a2.y + a3.y)) + ((a4.y + a5.y) + (a6.y + a7.y));
    a0.z = ((a0.z + a1.z) + (a2.z + a3.z)) + ((a4.z + a5.z) + (a6.z + a7.z));
    a0.w = ((a0.w + a1.w) + (a2.w + a3.w)) + ((a4.w + a5.w) + (a6.w + a7.w));
    if (nv) ((float4*)out)[(size_t)node * 32 + l] = a0;
}

// final-layer: out[i] = sigmoid(t[i] + sum_{j->i} t[j] + bias), t is N x 64 fp16.
// fp16 rounding of t: dz ~ sqrt(deg)*2^-11*t_rms ~ 0.008 -> out err <= 0.002.

template <typename IT>
__global__ __launch_bounds__(256) void agg_out_kernel(const _Float16* __restrict__ t,
                                                      const int* __restrict__ rowp,
                                                      const IT* __restrict__ srcs,
                                                      const float* __restrict__ bias,
                                                      float* __restrict__ out, int N) {
    int lane = threadIdx.x & 63;
    int node = blockIdx.x * 4 + (threadIdx.x >> 6);
    if (node >= N) return;
    int beg = rowp[node], end = rowp[node + 1];
    float a0 = (float)t[(size_t)node * 64 + lane];
    float a1 = 0.f, a2 = 0.f, a3 = 0.f, a4 = 0.f, a5 = 0.f, a6 = 0.f, a7 = 0.f;
    int p = beg;
    for (; p + 8 <= end; p += 8) {
        int s0 = (int)srcs[p + 0];
        int s1 = (int)srcs[p + 1];
        int s2 = (int)srcs[p + 2];
        int s3 = (int)srcs[p + 3];
        int s4 = (int)srcs[p + 4];
        int s5 = (int)srcs[p + 5];
        int s6 = (int)srcs[p + 6];
        int s7 = (int)srcs[p + 7];
        a0 += (float)t[(size_t)s0 * 64 + lane];
        a1 += (float)t[(size_t)s1 * 64 + lane];
        a2 += (float)t[(size_t)s2 * 64 + lane];
        a3 += (float)t[(size_t)s3 * 64 + lane];
        a4 += (float)t[(size_t)s4 * 64 + lane];
        a5 += (float)t[(size_t)s5 * 64 + lane];
        a6 += (float)t[(size_t)s6 * 64 + lane];
        a7 += (float)t[(size_t)s7 * 64 + lane];
    }
    for (; p < end; ++p) a0 += (float)t[(size_t)(int)srcs[p] * 64 + lane];
    float z = a0 + ((a1 + a2) + (a3 + a4)) + ((a5 + a6) + a7) + bias[lane];
    out[(size_t)node * 64 + lane] = 1.f / (1.f + __expf(-z));
}

// ---------------- MFMA MLP: out = relu(relu(in @ Wa + ba) @ Wb + bb) ----------------
// bf16 hi/lo split, 3 MFMA terms. 64 rows/block, 4 waves, wave owns 16 rows.
// NEW: W hi-plane staged in LDS (32 KB, shared by all 4 waves) -> per-block
// B-fragment L2 traffic 512->160 KB. LDS 33+32=66 KB -> 2 blocks/CU.

__device__ __forceinline__ void cvt8(const float4 p, const float4 q,
                                     bf16x8& hi, bf16x8& lo) {
    unsigned short hb; float hf;
#define CVT1(IDX, V) \
    hb = bf16_rne(V); hf = __uint_as_float(((unsigned int)hb) << 16); \
    hi[IDX] = (short)hb; lo[IDX] = (short)bf16_rne((V) - hf);
    CVT1(0, p.x) CVT1(1, p.y) CVT1(2, p.z) CVT1(3, p.w)
    CVT1(4, q.x) CVT1(5, q.y) CVT1(6, q.z) CVT1(7, q.w)
#undef CVT1
}

template <bool WRITE_GLOBAL>
__device__ __forceinline__ void gemm_phase_mfma(float* __restrict__ myrows,
                                                const short* whi_lds,
                                                const short* __restrict__ wlo,
                                                const float* __restrict__ bias,
                                                int arow, int agrp,
                                                int l, float* __restrict__ gout,
                                                int row_base, int N) {
    f32x4 acc[8];
#pragma unroll
    for (int ct = 0; ct < 8; ++ct) acc[ct] = (f32x4){0.f, 0.f, 0.f, 0.f};

#pragma unroll
    for (int kc = 0; kc < 4; ++kc) {
        const float* ap = &myrows[arow * 132 + kc * 32 + agrp * 8];
        float4 p = *(const float4*)ap;
        float4 q = *(const float4*)(ap + 4);
        bf16x8 ahi, alo;
        cvt8(p, q, ahi, alo);
#pragma unroll
        for (int ct = 0; ct < 8; ++ct) {
            const int off = ((ct * 4 + kc) << 9) + (l << 3);
            bf16x8 bhi = *(const bf16x8*)(whi_lds + off);
            bf16x8 blo = *(const bf16x8*)(wlo + off);
            acc[ct] = __builtin_amdgcn_mfma_f32_16x16x32_bf16(ahi, bhi, acc[ct], 0, 0, 0);
            acc[ct] = __builtin_amdgcn_mfma_f32_16x16x32_bf16(alo, bhi, acc[ct], 0, 0, 0);
            acc[ct] = __builtin_amdgcn_mfma_f32_16x16x32_bf16(ahi, blo, acc[ct], 0, 0, 0);
        }
    }

#pragma unroll
    for (int ct = 0; ct < 8; ++ct) {
        float bv = bias[ct * 16 + arow];  // D col = ct*16 + (lane&15)
#pragma unroll
        for (int r = 0; r < 4; ++r) {
            float v = fmaxf(acc[ct][r] + bv, 0.f);  // D row = agrp*4 + r
            if (WRITE_GLOBAL) {
                int row = row_base + agrp * 4 + r;
                if (row < N) gout[(size_t)row * 128 + ct * 16 + arow] = v;
            } else {
                myrows[(agrp * 4 + r) * 132 + ct * 16 + arow] = v;
            }
        }
    }
}

__global__ __launch_bounds__(256, 2) void mlp2_mfma_kernel(
    const float* __restrict__ in,
    const short* __restrict__ wpa, const float* __restrict__ ba,
    const short* __restrict__ wpb, const float* __restrict__ bb,
    float* __restrict__ out, int N) {
    __shared__ float sh[64 * 132];   // 33 KB A tile
    __shared__ short wsh[16384];     // 32 KB W hi-plane
    const int tid = threadIdx.x;
    const int wave = tid >> 6;
    const int l = tid & 63;
    const int arow = l & 15;
    const int agrp = l >> 4;
    const int row0 = blockIdx.x * 64;

    const float4* in4 = (const float4*)in;
#pragma unroll
    for (int it = 0; it < 8; ++it) {
        int i = tid + it * 256;
        int r = i >> 5, c = i & 31;
        int row = row0 + r;
        float4 z = {0.f, 0.f, 0.f, 0.f};
        float4 v = (row < N) ? in4[(size_t)row * 32 + c] : z;
        *(float4*)&sh[r * 132 + c * 4] = v;
    }
    // stage Wa hi-plane (16384 shorts = 2048 int4)
    {
        const int4* src = (const int4*)wpa;
        int4* dst = (int4*)wsh;
#pragma unroll
        for (int i = 0; i < 8; ++i) dst[tid + i * 256] = src[tid + i * 256];
    }
    __syncthreads();

    float* myrows = &sh[wave * 16 * 132];
    gemm_phase_mfma<false>(myrows, wsh, wpa + 16384, ba, arow, agrp, l, nullptr, 0, N);
    __syncthreads();
    // stage Wb hi-plane
    {
        const int4* src = (const int4*)wpb;
        int4* dst = (int4*)wsh;
#pragma unroll
        for (int i = 0; i < 8; ++i) dst[tid + i * 256] = src[tid + i * 256];
    }
    __syncthreads();
    gemm_phase_mfma<true>(myrows, wsh, wpb + 16384, bb, arow, agrp, l, out,
                          row0 + wave * 16, N);
}

// ---------------- last layer: t = in @ W (J=64), emit fp16 ----------------

__global__ __launch_bounds__(256, 6) void gemm64_kernel(const float* __restrict__ in,
                                                        const float* __restrict__ W,
                                                        _Float16* __restrict__ out, int N) {
    constexpr int TX = 16, RPT = 2;
    __shared__ float4 sh[32 * 32];

    int tid = threadIdx.x;
    int tx = tid % TX;
    int ty = tid / TX;
    int row0 = blockIdx.x * 32;

    const float4* in4 = (const float4*)in;
    for (int i = tid; i < 32 * 32; i += 256) {
        int r = i >> 5, c = i & 31;
        int row = row0 + r;
        float4 z = {0.f, 0.f, 0.f, 0.f};
        sh[i] = (row < N) ? in4[(size_t)row * 32 + c] : z;
    }
    __syncthreads();

    const float4* W4 = (const float4*)W;
    float acc[RPT][4];
#pragma unroll
    for (int r = 0; r < RPT; ++r)
#pragma unroll
        for (int c = 0; c < 4; ++c) acc[r][c] = 0.f;

#pragma unroll 4
    for (int kk = 0; kk < 128; kk += 4) {
        float4 w0 = W4[(kk + 0) * TX + tx];
        float4 w1 = W4[(kk + 1) * TX + tx];
        float4 w2 = W4[(kk + 2) * TX + tx];
        float4 w3 = W4[(kk + 3) * TX + tx];
#pragma unroll
        for (int r = 0; r < RPT; ++r) {
            float4 hv = sh[(ty * RPT + r) * 32 + (kk >> 2)];
            acc[r][0] += hv.x * w0.x + hv.y * w1.x + hv.z * w2.x + hv.w * w3.x;
            acc[r][1] += hv.x * w0.y + hv.y * w1.y + hv.z * w2.y + hv.w * w3.y;
            acc[r][2] += hv.x * w0.z + hv.y * w1.z + hv.z * w2.z + hv.w * w3.z;
            acc[r][3] += hv.x * w0.w + hv.y * w1.w + hv.z * w2.w + hv.w * w3.w;
        }
    }

#pragma unroll
    for (int r = 0; r < RPT; ++r) {
        int row = row0 + ty * RPT + r;
        if (row < N) {
            f16x4 v;
            v[0] = (_Float16)acc[r][0];
            v[1] = (_Float16)acc[r][1];
            v[2] = (_Float16)acc[r][2];
            v[3] = (_Float16)acc[r][3];
            *(f16x4*)&out[(size_t)row * 64 + tx * 4] = v;
        }
    }
}

// ---------------- orchestration ----------------

template <typename IT>
static void run_graph(const float* x, const int* ei, int N, int E,
                      const float* w0a, const float* b0a, const float* w0b, const float* b0b,
                      const float* wma, const float* bma, const float* wmb, const float* bmb,
                      const float* wl, const float* bl,
                      float* A, float* B, int* deg, int* rowp, int* cur, int* bsum,
                      IT* srcs, short* wpack, float* out, hipStream_t stream) {
    const int NB = (N + 255) / 256;
    dim3 blk(256);

    pack_w_kernel<<<(10 * 16384 + 255) / 256, blk, 0, stream>>>(w0a, w0b, wma, wmb, wpack);

    hipMemsetAsync(deg, 0, (size_t)N * sizeof(int), stream);
    hist_kernel<<<(E + 255) / 256, blk, 0, stream>>>(ei, E, deg);
    scan1_kernel<<<NB, blk, 0, stream>>>(deg, rowp, bsum, N);
    scan2_kernel<<<1, blk, 0, stream>>>(bsum, NB);
    scan3_kernel<<<NB, blk, 0, stream>>>(rowp, bsum, cur, N, E);
    scatter_kernel<IT><<<(E + 255) / 256, blk, 0, stream>>>(ei, E, cur, srcs);

    const int agg_grid  = (N + 7) / 8;
    const int aggo_grid = (N + 3) / 4;
    const int m64_grid  = (N + 63) / 64;
    const int g32_grid  = (N + 31) / 32;

    // layer 0
    agg_kernel<IT><<<agg_grid, blk, 0, stream>>>(x, rowp, srcs, A, N);
    mlp2_mfma_kernel<<<m64_grid, blk, 0, stream>>>(A, wpack + 0, b0a,
                                                   wpack + 32768, b0b, B, N);

    // middle layers 1..4
    float* h = B;
    float* o = A;
    for (int l = 0; l < 4; ++l) {
        const short* wpa = wpack + (size_t)(2 + l) * 32768;
        const short* wpb = wpack + (size_t)(6 + l) * 32768;
        const float* ba = bma + (size_t)l * HDIM;
        const float* bb = bmb + (size_t)l * HDIM;
        agg_kernel<IT><<<agg_grid, blk, 0, stream>>>(h, rowp, srcs, o, N);
        mlp2_mfma_kernel<<<m64_grid, blk, 0, stream>>>(o, wpa, ba, wpb, bb, h, N);
    }

    // last layer: t = h @ wl (fp16) ; out = sigmoid(t + S t + bl)
    _Float16* t16 = (_Float16*)o;
    gemm64_kernel<<<g32_grid, blk, 0, stream>>>(h, wl, t16, N);
    agg_out_kernel<IT><<<aggo_grid, blk, 0, stream>>>(t16, rowp, srcs, bl, out, N);
}

extern "C" void kernel_launch(void* const* d_in, const int* in_sizes, int n_in,
                              void* d_out, int out_size, void* d_ws, size_t ws_size,
                              hipStream_t stream) {
    const float* x   = (const float*)d_in[0];
    const int*   ei  = (const int*)d_in[1];
    const float* w0a = (const float*)d_in[2];
    const float* b0a = (const float*)d_in[3];
    const float* w0b = (const float*)d_in[4];
    const float* b0b = (const float*)d_in[5];
    const float* wma = (const float*)d_in[6];
    const float* bma = (const float*)d_in[7];
    const float* wmb = (const float*)d_in[8];
    const float* bmb = (const float*)d_in[9];
    const float* wl  = (const float*)d_in[10];
    const float* bl  = (const float*)d_in[11];

    const int N = in_sizes[0] / HDIM;
    const int E = in_sizes[1] / 2;

    // workspace layout
    float* A = (float*)d_ws;
    float* B = A + (size_t)N * HDIM;
    int* deg  = (int*)(B + (size_t)N * HDIM);
    int* rowp = deg + N;
    int* cur  = rowp + N + 1;
    int* bsum = cur + N;
    int* srcs = bsum + 256;              // E ints of space (ushort uses half)
    short* wpack = (short*)(srcs + E);   // 10 * 32768 shorts = 640 KiB

    if (N <= 65535) {
        run_graph<unsigned short>(x, ei, N, E, w0a, b0a, w0b, b0b, wma, bma, wmb, bmb,
                                  wl, bl, A, B, deg, rowp, cur, bsum,
                                  (unsigned short*)srcs, wpack, (float*)d_out, stream);
    } else {
        run_graph<int>(x, ei, N, E, w0a, b0a, w0b, b0b, wma, bma, wmb, bmb,
                       wl, bl, A, B, deg, rowp, cur, bsum,
                       srcs, wpack, (float*)d_out, stream);
    }
}

// Round 13
// 586.784 us; speedup vs baseline: 1.0584x; 1.0584x over previous
//
#include <hip/hip_runtime.h>
#include <hip/hip_bf16.h>

#define HDIM 128

typedef __attribute__((ext_vector_type(8))) short bf16x8;
typedef __attribute__((ext_vector_type(4))) float f32x4;
typedef __attribute__((ext_vector_type(4))) _Float16 f16x4;

__device__ __forceinline__ unsigned short bf16_rne(float x) {
    unsigned int u = __float_as_uint(x);
    unsigned int r = u + 0x7FFFu + ((u >> 16) & 1u);
    return (unsigned short)(r >> 16);
}

// ---------------- CSR build ----------------

__global__ __launch_bounds__(256) void hist_kernel(const int* __restrict__ ei, int E,
                                                   int* __restrict__ deg) {
    int e = blockIdx.x * 256 + threadIdx.x;
    if (e < E) atomicAdd(&deg[ei[E + e]], 1);  // dst = ei[1][e]
}

__global__ __launch_bounds__(256) void scan1_kernel(const int* __restrict__ deg,
                                                    int* __restrict__ rowp,
                                                    int* __restrict__ bsum, int N) {
    __shared__ int s[256];
    int t = threadIdx.x;
    int i = blockIdx.x * 256 + t;
    int v = (i < N) ? deg[i] : 0;
    s[t] = v; __syncthreads();
    for (int off = 1; off < 256; off <<= 1) {
        int x = (t >= off) ? s[t - off] : 0;
        __syncthreads();
        s[t] += x;
        __syncthreads();
    }
    if (i < N) rowp[i] = s[t] - v;           // local exclusive
    if (t == 255) bsum[blockIdx.x] = s[255]; // block total
}

__global__ __launch_bounds__(256) void scan2_kernel(int* __restrict__ bsum, int NB) {
    __shared__ int s[256];
    int t = threadIdx.x;
    int v = (t < NB) ? bsum[t] : 0;
    s[t] = v; __syncthreads();
    for (int off = 1; off < 256; off <<= 1) {
        int x = (t >= off) ? s[t - off] : 0;
        __syncthreads();
        s[t] += x;
        __syncthreads();
    }
    if (t < NB) bsum[t] = s[t] - v;          // exclusive block offsets
}

__global__ __launch_bounds__(256) void scan3_kernel(int* __restrict__ rowp,
                                                    const int* __restrict__ bsum,
                                                    int* __restrict__ cur, int N, int E) {
    int i = blockIdx.x * 256 + threadIdx.x;
    if (i < N) {
        int r = rowp[i] + bsum[blockIdx.x];
        rowp[i] = r;
        cur[i] = r;
    }
    if (i == 0) rowp[N] = E;
}

template <typename IT>
__global__ __launch_bounds__(256) void scatter_kernel(const int* __restrict__ ei, int E,
                                                      int* __restrict__ cur,
                                                      IT* __restrict__ srcs) {
    int e = blockIdx.x * 256 + threadIdx.x;
    if (e < E) {
        int d = ei[E + e];
        int p = atomicAdd(&cur[d], 1);
        srcs[p] = (IT)ei[e];  // src = ei[0][e]
    }
}

// ---------------- W pre-pack into MFMA B-fragment order, bf16 hi/lo ----------------

__global__ __launch_bounds__(256) void pack_w_kernel(const float* __restrict__ w0a,
                                                     const float* __restrict__ w0b,
                                                     const float* __restrict__ wma,
                                                     const float* __restrict__ wmb,
                                                     short* __restrict__ wpack) {
    int idx = blockIdx.x * 256 + threadIdx.x;
    if (idx >= 10 * 16384) return;
    int mat = idx >> 14;           // 0..9
    int rem = idx & 16383;
    int i = rem & 7;
    int lane = (rem >> 3) & 63;
    int kc = (rem >> 9) & 3;
    int ct = rem >> 11;
    const float* W = (mat == 0) ? w0a
                   : (mat == 1) ? w0b
                   : (mat < 6)  ? (wma + (size_t)(mat - 2) * 16384)
                                : (wmb + (size_t)(mat - 6) * 16384);
    int k = kc * 32 + (lane >> 4) * 8 + i;
    int col = ct * 16 + (lane & 15);
    float x = W[k * 128 + col];
    unsigned short hb = bf16_rne(x);
    float hf = __uint_as_float(((unsigned int)hb) << 16);
    unsigned short lb = bf16_rne(x - hf);
    wpack[(size_t)mat * 32768 + rem] = (short)hb;
    wpack[(size_t)mat * 32768 + 16384 + rem] = (short)lb;
}

// ---------------- aggregation: out[i] = h[i] + sum_{j->i} h[j] ----------------
// Structural wall (~59us): each XCD L2 must stream all of h (random gather).

template <typename IT>
__global__ __launch_bounds__(256) void agg_kernel(const float* __restrict__ h,
                                                  const int* __restrict__ rowp,
                                                  const IT* __restrict__ srcs,
                                                  float* __restrict__ out, int N) {
    const int tid  = threadIdx.x;
    const int lane = tid & 63;
    const int half = lane >> 5;
    const int l    = lane & 31;
    const int node = blockIdx.x * 8 + ((tid >> 6) << 1) + half;
    const bool nv  = node < N;
    const int nc   = nv ? node : 0;

    const float4* h4 = (const float4*)h;
    int beg = rowp[nc];
    int end = nv ? rowp[nc + 1] : beg;
    int em1 = max(end - 1, 0);

    const float4 z = {0.f, 0.f, 0.f, 0.f};
    float4 a0 = nv ? h4[(size_t)nc * 32 + l] : z;
    float4 a1 = z, a2 = z, a3 = z, a4 = z, a5 = z, a6 = z, a7 = z;

    for (int q = beg; q < end; q += 8) {
        int c0 = min(q + 0, em1);
        int c1 = min(q + 1, em1);
        int c2 = min(q + 2, em1);
        int c3 = min(q + 3, em1);
        int c4 = min(q + 4, em1);
        int c5 = min(q + 5, em1);
        int c6 = min(q + 6, em1);
        int c7 = min(q + 7, em1);
        int s0 = (int)srcs[c0];
        int s1 = (int)srcs[c1];
        int s2 = (int)srcs[c2];
        int s3 = (int)srcs[c3];
        int s4 = (int)srcs[c4];
        int s5 = (int)srcs[c5];
        int s6 = (int)srcs[c6];
        int s7 = (int)srcs[c7];
        float4 v0 = h4[(size_t)s0 * 32 + l];
        float4 v1 = h4[(size_t)s1 * 32 + l];
        float4 v2 = h4[(size_t)s2 * 32 + l];
        float4 v3 = h4[(size_t)s3 * 32 + l];
        float4 v4 = h4[(size_t)s4 * 32 + l];
        float4 v5 = h4[(size_t)s5 * 32 + l];
        float4 v6 = h4[(size_t)s6 * 32 + l];
        float4 v7 = h4[(size_t)s7 * 32 + l];
        float m0 = (q + 0 < end) ? 1.f : 0.f;
        float m1 = (q + 1 < end) ? 1.f : 0.f;
        float m2 = (q + 2 < end) ? 1.f : 0.f;
        float m3 = (q + 3 < end) ? 1.f : 0.f;
        float m4 = (q + 4 < end) ? 1.f : 0.f;
        float m5 = (q + 5 < end) ? 1.f : 0.f;
        float m6 = (q + 6 < end) ? 1.f : 0.f;
        float m7 = (q + 7 < end) ? 1.f : 0.f;
        a0.x = fmaf(v0.x, m0, a0.x); a0.y = fmaf(v0.y, m0, a0.y);
        a0.z = fmaf(v0.z, m0, a0.z); a0.w = fmaf(v0.w, m0, a0.w);
        a1.x = fmaf(v1.x, m1, a1.x); a1.y = fmaf(v1.y, m1, a1.y);
        a1.z = fmaf(v1.z, m1, a1.z); a1.w = fmaf(v1.w, m1, a1.w);
        a2.x = fmaf(v2.x, m2, a2.x); a2.y = fmaf(v2.y, m2, a2.y);
        a2.z = fmaf(v2.z, m2, a2.z); a2.w = fmaf(v2.w, m2, a2.w);
        a3.x = fmaf(v3.x, m3, a3.x); a3.y = fmaf(v3.y, m3, a3.y);
        a3.z = fmaf(v3.z, m3, a3.z); a3.w = fmaf(v3.w, m3, a3.w);
        a4.x = fmaf(v4.x, m4, a4.x); a4.y = fmaf(v4.y, m4, a4.y);
        a4.z = fmaf(v4.z, m4, a4.z); a4.w = fmaf(v4.w, m4, a4.w);
        a5.x = fmaf(v5.x, m5, a5.x); a5.y = fmaf(v5.y, m5, a5.y);
        a5.z = fmaf(v5.z, m5, a5.z); a5.w = fmaf(v5.w, m5, a5.w);
        a6.x = fmaf(v6.x, m6, a6.x); a6.y = fmaf(v6.y, m6, a6.y);
        a6.z = fmaf(v6.z, m6, a6.z); a6.w = fmaf(v6.w, m6, a6.w);
        a7.x = fmaf(v7.x, m7, a7.x); a7.y = fmaf(v7.y, m7, a7.y);
        a7.z = fmaf(v7.z, m7, a7.z); a7.w = fmaf(v7.w, m7, a7.w);
    }

    a0.x = ((a0.x + a1.x) + (a2.x + a3.x)) + ((a4.x + a5.x) + (a6.x + a7.x));
    a0.y = ((a0.y + a1.y) + (a2.y + a3.y)) + ((a4.y + a5.y) + (a6.y + a7.y));
    a0.z = ((a0.z + a1.z) + (a2.z + a3.z)) + ((a4.z + a5.z) + (a6.z + a7.z));
    a0.w = ((a0.w + a1.w) + (a2.w + a3.w)) + ((a4.w + a5.w) + (a6.w + a7.w));
    if (nv) ((float4*)out)[(size_t)node * 32 + l] = a0;
}

// final-layer: out[i] = sigmoid(t[i] + sum_{j->i} t[j] + bias), t is N x 64 fp16.
// fp16 rounding of t: dz ~ sqrt(deg)*2^-11*t_rms ~ 0.008 -> out err <= 0.002.

template <typename IT>
__global__ __launch_bounds__(256) void agg_out_kernel(const _Float16* __restrict__ t,
                                                      const int* __restrict__ rowp,
                                                      const IT* __restrict__ srcs,
                                                      const float* __restrict__ bias,
                                                      float* __restrict__ out, int N) {
    int lane = threadIdx.x & 63;
    int node = blockIdx.x * 4 + (threadIdx.x >> 6);
    if (node >= N) return;
    int beg = rowp[node], end = rowp[node + 1];
    float a0 = (float)t[(size_t)node * 64 + lane];
    float a1 = 0.f, a2 = 0.f, a3 = 0.f, a4 = 0.f, a5 = 0.f, a6 = 0.f, a7 = 0.f;
    int p = beg;
    for (; p + 8 <= end; p += 8) {
        int s0 = (int)srcs[p + 0];
        int s1 = (int)srcs[p + 1];
        int s2 = (int)srcs[p + 2];
        int s3 = (int)srcs[p + 3];
        int s4 = (int)srcs[p + 4];
        int s5 = (int)srcs[p + 5];
        int s6 = (int)srcs[p + 6];
        int s7 = (int)srcs[p + 7];
        a0 += (float)t[(size_t)s0 * 64 + lane];
        a1 += (float)t[(size_t)s1 * 64 + lane];
        a2 += (float)t[(size_t)s2 * 64 + lane];
        a3 += (float)t[(size_t)s3 * 64 + lane];
        a4 += (float)t[(size_t)s4 * 64 + lane];
        a5 += (float)t[(size_t)s5 * 64 + lane];
        a6 += (float)t[(size_t)s6 * 64 + lane];
        a7 += (float)t[(size_t)s7 * 64 + lane];
    }
    for (; p < end; ++p) a0 += (float)t[(size_t)(int)srcs[p] * 64 + lane];
    float z = a0 + ((a1 + a2) + (a3 + a4)) + ((a5 + a6) + a7) + bias[lane];
    out[(size_t)node * 64 + lane] = 1.f / (1.f + __expf(-z));
}

// ---------------- MFMA MLP: out = relu(relu(in @ Wa + ba) @ Wb + bb) ----------------
// bf16 hi/lo split, 3 MFMA terms. 64 rows/block, 4 waves, wave owns 16 rows.
// R11 config (best measured): 33 KB LDS, W from L2, 4 blocks/CU.

__device__ __forceinline__ void cvt8(const float4 p, const float4 q,
                                     bf16x8& hi, bf16x8& lo) {
    unsigned short hb; float hf;
#define CVT1(IDX, V) \
    hb = bf16_rne(V); hf = __uint_as_float(((unsigned int)hb) << 16); \
    hi[IDX] = (short)hb; lo[IDX] = (short)bf16_rne((V) - hf);
    CVT1(0, p.x) CVT1(1, p.y) CVT1(2, p.z) CVT1(3, p.w)
    CVT1(4, q.x) CVT1(5, q.y) CVT1(6, q.z) CVT1(7, q.w)
#undef CVT1
}

template <bool WRITE_GLOBAL>
__device__ __forceinline__ void gemm_phase_mfma(float* __restrict__ myrows,
                                                const short* __restrict__ wp,
                                                const float* __restrict__ bias,
                                                int arow, int agrp,
                                                int l, float* __restrict__ gout,
                                                int row_base, int N) {
    f32x4 acc[8];
#pragma unroll
    for (int ct = 0; ct < 8; ++ct) acc[ct] = (f32x4){0.f, 0.f, 0.f, 0.f};

    const short* wlo = wp + 16384;
#pragma unroll
    for (int kc = 0; kc < 4; ++kc) {
        const float* ap = &myrows[arow * 132 + kc * 32 + agrp * 8];
        float4 p = *(const float4*)ap;
        float4 q = *(const float4*)(ap + 4);
        bf16x8 ahi, alo;
        cvt8(p, q, ahi, alo);
#pragma unroll
        for (int ct = 0; ct < 8; ++ct) {
            const int off = ((ct * 4 + kc) << 9) + (l << 3);
            bf16x8 bhi = *(const bf16x8*)(wp + off);
            bf16x8 blo = *(const bf16x8*)(wlo + off);
            acc[ct] = __builtin_amdgcn_mfma_f32_16x16x32_bf16(ahi, bhi, acc[ct], 0, 0, 0);
            acc[ct] = __builtin_amdgcn_mfma_f32_16x16x32_bf16(alo, bhi, acc[ct], 0, 0, 0);
            acc[ct] = __builtin_amdgcn_mfma_f32_16x16x32_bf16(ahi, blo, acc[ct], 0, 0, 0);
        }
    }

#pragma unroll
    for (int ct = 0; ct < 8; ++ct) {
        float bv = bias[ct * 16 + arow];  // D col = ct*16 + (lane&15)
#pragma unroll
        for (int r = 0; r < 4; ++r) {
            float v = fmaxf(acc[ct][r] + bv, 0.f);  // D row = agrp*4 + r
            if (WRITE_GLOBAL) {
                int row = row_base + agrp * 4 + r;
                if (row < N) gout[(size_t)row * 128 + ct * 16 + arow] = v;
            } else {
                myrows[(agrp * 4 + r) * 132 + ct * 16 + arow] = v;
            }
        }
    }
}

__global__ __launch_bounds__(256, 4) void mlp2_mfma_kernel(
    const float* __restrict__ in,
    const short* __restrict__ wpa, const float* __restrict__ ba,
    const short* __restrict__ wpb, const float* __restrict__ bb,
    float* __restrict__ out, int N) {
    __shared__ float sh[64 * 132];
    const int tid = threadIdx.x;
    const int wave = tid >> 6;
    const int l = tid & 63;
    const int arow = l & 15;
    const int agrp = l >> 4;
    const int row0 = blockIdx.x * 64;

    const float4* in4 = (const float4*)in;
#pragma unroll
    for (int it = 0; it < 8; ++it) {
        int i = tid + it * 256;
        int r = i >> 5, c = i & 31;
        int row = row0 + r;
        float4 z = {0.f, 0.f, 0.f, 0.f};
        float4 v = (row < N) ? in4[(size_t)row * 32 + c] : z;
        *(float4*)&sh[r * 132 + c * 4] = v;
    }
    __syncthreads();

    float* myrows = &sh[wave * 16 * 132];
    gemm_phase_mfma<false>(myrows, wpa, ba, arow, agrp, l, nullptr, 0, N);
    __syncthreads();
    gemm_phase_mfma<true>(myrows, wpb, bb, arow, agrp, l, out, row0 + wave * 16, N);
}

// ---------------- last layer: t = in @ W (J=64), emit fp16 ----------------

__global__ __launch_bounds__(256, 6) void gemm64_kernel(const float* __restrict__ in,
                                                        const float* __restrict__ W,
                                                        _Float16* __restrict__ out, int N) {
    constexpr int TX = 16, RPT = 2;
    __shared__ float4 sh[32 * 32];

    int tid = threadIdx.x;
    int tx = tid % TX;
    int ty = tid / TX;
    int row0 = blockIdx.x * 32;

    const float4* in4 = (const float4*)in;
    for (int i = tid; i < 32 * 32; i += 256) {
        int r = i >> 5, c = i & 31;
        int row = row0 + r;
        float4 z = {0.f, 0.f, 0.f, 0.f};
        sh[i] = (row < N) ? in4[(size_t)row * 32 + c] : z;
    }
    __syncthreads();

    const float4* W4 = (const float4*)W;
    float acc[RPT][4];
#pragma unroll
    for (int r = 0; r < RPT; ++r)
#pragma unroll
        for (int c = 0; c < 4; ++c) acc[r][c] = 0.f;

#pragma unroll 4
    for (int kk = 0; kk < 128; kk += 4) {
        float4 w0 = W4[(kk + 0) * TX + tx];
        float4 w1 = W4[(kk + 1) * TX + tx];
        float4 w2 = W4[(kk + 2) * TX + tx];
        float4 w3 = W4[(kk + 3) * TX + tx];
#pragma unroll
        for (int r = 0; r < RPT; ++r) {
            float4 hv = sh[(ty * RPT + r) * 32 + (kk >> 2)];
            acc[r][0] += hv.x * w0.x + hv.y * w1.x + hv.z * w2.x + hv.w * w3.x;
            acc[r][1] += hv.x * w0.y + hv.y * w1.y + hv.z * w2.y + hv.w * w3.y;
            acc[r][2] += hv.x * w0.z + hv.y * w1.z + hv.z * w2.z + hv.w * w3.z;
            acc[r][3] += hv.x * w0.w + hv.y * w1.w + hv.z * w2.w + hv.w * w3.w;
        }
    }

#pragma unroll
    for (int r = 0; r < RPT; ++r) {
        int row = row0 + ty * RPT + r;
        if (row < N) {
            f16x4 v;
            v[0] = (_Float16)acc[r][0];
            v[1] = (_Float16)acc[r][1];
            v[2] = (_Float16)acc[r][2];
            v[3] = (_Float16)acc[r][3];
            *(f16x4*)&out[(size_t)row * 64 + tx * 4] = v;
        }
    }
}

// ---------------- orchestration ----------------

template <typename IT>
static void run_graph(const float* x, const int* ei, int N, int E,
                      const float* w0a, const float* b0a, const float* w0b, const float* b0b,
                      const float* wma, const float* bma, const float* wmb, const float* bmb,
                      const float* wl, const float* bl,
                      float* A, float* B, int* deg, int* rowp, int* cur, int* bsum,
                      IT* srcs, short* wpack, float* out, hipStream_t stream) {
    const int NB = (N + 255) / 256;
    dim3 blk(256);

    pack_w_kernel<<<(10 * 16384 + 255) / 256, blk, 0, stream>>>(w0a, w0b, wma, wmb, wpack);

    hipMemsetAsync(deg, 0, (size_t)N * sizeof(int), stream);
    hist_kernel<<<(E + 255) / 256, blk, 0, stream>>>(ei, E, deg);
    scan1_kernel<<<NB, blk, 0, stream>>>(deg, rowp, bsum, N);
    scan2_kernel<<<1, blk, 0, stream>>>(bsum, NB);
    scan3_kernel<<<NB, blk, 0, stream>>>(rowp, bsum, cur, N, E);
    scatter_kernel<IT><<<(E + 255) / 256, blk, 0, stream>>>(ei, E, cur, srcs);

    const int agg_grid  = (N + 7) / 8;
    const int aggo_grid = (N + 3) / 4;
    const int m64_grid  = (N + 63) / 64;
    const int g32_grid  = (N + 31) / 32;

    // layer 0
    agg_kernel<IT><<<agg_grid, blk, 0, stream>>>(x, rowp, srcs, A, N);
    mlp2_mfma_kernel<<<m64_grid, blk, 0, stream>>>(A, wpack + 0, b0a,
                                                   wpack + 32768, b0b, B, N);

    // middle layers 1..4
    float* h = B;
    float* o = A;
    for (int l = 0; l < 4; ++l) {
        const short* wpa = wpack + (size_t)(2 + l) * 32768;
        const short* wpb = wpack + (size_t)(6 + l) * 32768;
        const float* ba = bma + (size_t)l * HDIM;
        const float* bb = bmb + (size_t)l * HDIM;
        agg_kernel<IT><<<agg_grid, blk, 0, stream>>>(h, rowp, srcs, o, N);
        mlp2_mfma_kernel<<<m64_grid, blk, 0, stream>>>(o, wpa, ba, wpb, bb, h, N);
    }

    // last layer: t = h @ wl (fp16) ; out = sigmoid(t + S t + bl)
    _Float16* t16 = (_Float16*)o;
    gemm64_kernel<<<g32_grid, blk, 0, stream>>>(h, wl, t16, N);
    agg_out_kernel<IT><<<aggo_grid, blk, 0, stream>>>(t16, rowp, srcs, bl, out, N);
}

extern "C" void kernel_launch(void* const* d_in, const int* in_sizes, int n_in,
                              void* d_out, int out_size, void* d_ws, size_t ws_size,
                              hipStream_t stream) {
    const float* x   = (const float*)d_in[0];
    const int*   ei  = (const int*)d_in[1];
    const float* w0a = (const float*)d_in[2];
    const float* b0a = (const float*)d_in[3];
    const float* w0b = (const float*)d_in[4];
    const float* b0b = (const float*)d_in[5];
    const float* wma = (const float*)d_in[6];
    const float* bma = (const float*)d_in[7];
    const float* wmb = (const float*)d_in[8];
    const float* bmb = (const float*)d_in[9];
    const float* wl  = (const float*)d_in[10];
    const float* bl  = (const float*)d_in[11];

    const int N = in_sizes[0] / HDIM;
    const int E = in_sizes[1] / 2;

    // workspace layout
    float* A = (float*)d_ws;
    float* B = A + (size_t)N * HDIM;
    int* deg  = (int*)(B + (size_t)N * HDIM);
    int* rowp = deg + N;
    int* cur  = rowp + N + 1;
    int* bsum = cur + N;
    int* srcs = bsum + 256;              // E ints of space (ushort uses half)
    short* wpack = (short*)(srcs + E);   // 10 * 32768 shorts = 640 KiB

    if (N <= 65535) {
        run_graph<unsigned short>(x, ei, N, E, w0a, b0a, w0b, b0b, wma, bma, wmb, bmb,
                                  wl, bl, A, B, deg, rowp, cur, bsum,
                                  (unsigned short*)srcs, wpack, (float*)d_out, stream);
    } else {
        run_graph<int>(x, ei, N, E, w0a, b0a, w0b, b0b, wma, bma, wmb, bmb,
                       wl, bl, A, B, deg, rowp, cur, bsum,
                       srcs, wpack, (float*)d_out, stream);
    }
}

// Round 14
// 583.397 us; speedup vs baseline: 1.0646x; 1.0058x over previous
//
#include <hip/hip_runtime.h>
#include <hip/hip_bf16.h>

#define HDIM 128

typedef __attribute__((ext_vector_type(8))) short bf16x8;
typedef __attribute__((ext_vector_type(4))) float f32x4;
typedef __attribute__((ext_vector_type(4))) _Float16 f16x4;

// native-cast bf16 split: hi = bf16(x) (RNE, compiler emits cvt_pk), residual lo.
__device__ __forceinline__ void split_bf16(float x, short& hi, short& lo) {
    __bf16 h = (__bf16)x;
    unsigned short hb = __builtin_bit_cast(unsigned short, h);
    float hf = __uint_as_float(((unsigned int)hb) << 16);
    __bf16 lw = (__bf16)(x - hf);
    hi = (short)hb;
    lo = (short)__builtin_bit_cast(unsigned short, lw);
}

// ---------------- CSR build ----------------

__global__ __launch_bounds__(256) void hist_kernel(const int* __restrict__ ei, int E,
                                                   int* __restrict__ deg) {
    int e = blockIdx.x * 256 + threadIdx.x;
    if (e < E) atomicAdd(&deg[ei[E + e]], 1);  // dst = ei[1][e]
}

__global__ __launch_bounds__(256) void scan1_kernel(const int* __restrict__ deg,
                                                    int* __restrict__ rowp,
                                                    int* __restrict__ bsum, int N) {
    __shared__ int s[256];
    int t = threadIdx.x;
    int i = blockIdx.x * 256 + t;
    int v = (i < N) ? deg[i] : 0;
    s[t] = v; __syncthreads();
    for (int off = 1; off < 256; off <<= 1) {
        int x = (t >= off) ? s[t - off] : 0;
        __syncthreads();
        s[t] += x;
        __syncthreads();
    }
    if (i < N) rowp[i] = s[t] - v;           // local exclusive
    if (t == 255) bsum[blockIdx.x] = s[255]; // block total
}

__global__ __launch_bounds__(256) void scan2_kernel(int* __restrict__ bsum, int NB) {
    __shared__ int s[256];
    int t = threadIdx.x;
    int v = (t < NB) ? bsum[t] : 0;
    s[t] = v; __syncthreads();
    for (int off = 1; off < 256; off <<= 1) {
        int x = (t >= off) ? s[t - off] : 0;
        __syncthreads();
        s[t] += x;
        __syncthreads();
    }
    if (t < NB) bsum[t] = s[t] - v;          // exclusive block offsets
}

__global__ __launch_bounds__(256) void scan3_kernel(int* __restrict__ rowp,
                                                    const int* __restrict__ bsum,
                                                    int* __restrict__ cur, int N, int E) {
    int i = blockIdx.x * 256 + threadIdx.x;
    if (i < N) {
        int r = rowp[i] + bsum[blockIdx.x];
        rowp[i] = r;
        cur[i] = r;
    }
    if (i == 0) rowp[N] = E;
}

template <typename IT>
__global__ __launch_bounds__(256) void scatter_kernel(const int* __restrict__ ei, int E,
                                                      int* __restrict__ cur,
                                                      IT* __restrict__ srcs) {
    int e = blockIdx.x * 256 + threadIdx.x;
    if (e < E) {
        int d = ei[E + e];
        int p = atomicAdd(&cur[d], 1);
        srcs[p] = (IT)ei[e];  // src = ei[0][e]
    }
}

// ---------------- W pre-pack into MFMA B-fragment order, bf16 hi/lo ----------------

__global__ __launch_bounds__(256) void pack_w_kernel(const float* __restrict__ w0a,
                                                     const float* __restrict__ w0b,
                                                     const float* __restrict__ wma,
                                                     const float* __restrict__ wmb,
                                                     short* __restrict__ wpack) {
    int idx = blockIdx.x * 256 + threadIdx.x;
    if (idx >= 10 * 16384) return;
    int mat = idx >> 14;           // 0..9
    int rem = idx & 16383;
    int i = rem & 7;
    int lane = (rem >> 3) & 63;
    int kc = (rem >> 9) & 3;
    int ct = rem >> 11;
    const float* W = (mat == 0) ? w0a
                   : (mat == 1) ? w0b
                   : (mat < 6)  ? (wma + (size_t)(mat - 2) * 16384)
                                : (wmb + (size_t)(mat - 6) * 16384);
    int k = kc * 32 + (lane >> 4) * 8 + i;
    int col = ct * 16 + (lane & 15);
    float x = W[k * 128 + col];
    short hb, lb;
    split_bf16(x, hb, lb);
    wpack[(size_t)mat * 32768 + rem] = hb;
    wpack[(size_t)mat * 32768 + 16384 + rem] = lb;
}

// ---------------- aggregation: out[i] = h[i] + sum_{j->i} h[j] ----------------
// Structural wall (~59us): each XCD L2 must stream all of h (random gather).

template <typename IT>
__global__ __launch_bounds__(256) void agg_kernel(const float* __restrict__ h,
                                                  const int* __restrict__ rowp,
                                                  const IT* __restrict__ srcs,
                                                  float* __restrict__ out, int N) {
    const int tid  = threadIdx.x;
    const int lane = tid & 63;
    const int half = lane >> 5;
    const int l    = lane & 31;
    const int node = blockIdx.x * 8 + ((tid >> 6) << 1) + half;
    const bool nv  = node < N;
    const int nc   = nv ? node : 0;

    const float4* h4 = (const float4*)h;
    int beg = rowp[nc];
    int end = nv ? rowp[nc + 1] : beg;
    int em1 = max(end - 1, 0);

    const float4 z = {0.f, 0.f, 0.f, 0.f};
    float4 a0 = nv ? h4[(size_t)nc * 32 + l] : z;
    float4 a1 = z, a2 = z, a3 = z, a4 = z, a5 = z, a6 = z, a7 = z;

    for (int q = beg; q < end; q += 8) {
        int c0 = min(q + 0, em1);
        int c1 = min(q + 1, em1);
        int c2 = min(q + 2, em1);
        int c3 = min(q + 3, em1);
        int c4 = min(q + 4, em1);
        int c5 = min(q + 5, em1);
        int c6 = min(q + 6, em1);
        int c7 = min(q + 7, em1);
        int s0 = (int)srcs[c0];
        int s1 = (int)srcs[c1];
        int s2 = (int)srcs[c2];
        int s3 = (int)srcs[c3];
        int s4 = (int)srcs[c4];
        int s5 = (int)srcs[c5];
        int s6 = (int)srcs[c6];
        int s7 = (int)srcs[c7];
        float4 v0 = h4[(size_t)s0 * 32 + l];
        float4 v1 = h4[(size_t)s1 * 32 + l];
        float4 v2 = h4[(size_t)s2 * 32 + l];
        float4 v3 = h4[(size_t)s3 * 32 + l];
        float4 v4 = h4[(size_t)s4 * 32 + l];
        float4 v5 = h4[(size_t)s5 * 32 + l];
        float4 v6 = h4[(size_t)s6 * 32 + l];
        float4 v7 = h4[(size_t)s7 * 32 + l];
        float m0 = (q + 0 < end) ? 1.f : 0.f;
        float m1 = (q + 1 < end) ? 1.f : 0.f;
        float m2 = (q + 2 < end) ? 1.f : 0.f;
        float m3 = (q + 3 < end) ? 1.f : 0.f;
        float m4 = (q + 4 < end) ? 1.f : 0.f;
        float m5 = (q + 5 < end) ? 1.f : 0.f;
        float m6 = (q + 6 < end) ? 1.f : 0.f;
        float m7 = (q + 7 < end) ? 1.f : 0.f;
        a0.x = fmaf(v0.x, m0, a0.x); a0.y = fmaf(v0.y, m0, a0.y);
        a0.z = fmaf(v0.z, m0, a0.z); a0.w = fmaf(v0.w, m0, a0.w);
        a1.x = fmaf(v1.x, m1, a1.x); a1.y = fmaf(v1.y, m1, a1.y);
        a1.z = fmaf(v1.z, m1, a1.z); a1.w = fmaf(v1.w, m1, a1.w);
        a2.x = fmaf(v2.x, m2, a2.x); a2.y = fmaf(v2.y, m2, a2.y);
        a2.z = fmaf(v2.z, m2, a2.z); a2.w = fmaf(v2.w, m2, a2.w);
        a3.x = fmaf(v3.x, m3, a3.x); a3.y = fmaf(v3.y, m3, a3.y);
        a3.z = fmaf(v3.z, m3, a3.z); a3.w = fmaf(v3.w, m3, a3.w);
        a4.x = fmaf(v4.x, m4, a4.x); a4.y = fmaf(v4.y, m4, a4.y);
        a4.z = fmaf(v4.z, m4, a4.z); a4.w = fmaf(v4.w, m4, a4.w);
        a5.x = fmaf(v5.x, m5, a5.x); a5.y = fmaf(v5.y, m5, a5.y);
        a5.z = fmaf(v5.z, m5, a5.z); a5.w = fmaf(v5.w, m5, a5.w);
        a6.x = fmaf(v6.x, m6, a6.x); a6.y = fmaf(v6.y, m6, a6.y);
        a6.z = fmaf(v6.z, m6, a6.z); a6.w = fmaf(v6.w, m6, a6.w);
        a7.x = fmaf(v7.x, m7, a7.x); a7.y = fmaf(v7.y, m7, a7.y);
        a7.z = fmaf(v7.z, m7, a7.z); a7.w = fmaf(v7.w, m7, a7.w);
    }

    a0.x = ((a0.x + a1.x) + (a2.x + a3.x)) + ((a4.x + a5.x) + (a6.x + a7.x));
    a0.y = ((a0.y + a1.y) + (a2.y + a3.y)) + ((a4.y + a5.y) + (a6.y + a7.y));
    a0.z = ((a0.z + a1.z) + (a2.z + a3.z)) + ((a4.z + a5.z) + (a6.z + a7.z));
    a0.w = ((a0.w + a1.w) + (a2.w + a3.w)) + ((a4.w + a5.w) + (a6.w + a7.w));
    if (nv) ((float4*)out)[(size_t)node * 32 + l] = a0;
}

// final-layer: out[i] = sigmoid(t[i] + sum_{j->i} t[j] + bias), t is N x 64 fp16.

template <typename IT>
__global__ __launch_bounds__(256) void agg_out_kernel(const _Float16* __restrict__ t,
                                                      const int* __restrict__ rowp,
                                                      const IT* __restrict__ srcs,
                                                      const float* __restrict__ bias,
                                                      float* __restrict__ out, int N) {
    int lane = threadIdx.x & 63;
    int node = blockIdx.x * 4 + (threadIdx.x >> 6);
    if (node >= N) return;
    int beg = rowp[node], end = rowp[node + 1];
    float a0 = (float)t[(size_t)node * 64 + lane];
    float a1 = 0.f, a2 = 0.f, a3 = 0.f, a4 = 0.f, a5 = 0.f, a6 = 0.f, a7 = 0.f;
    int p = beg;
    for (; p + 8 <= end; p += 8) {
        int s0 = (int)srcs[p + 0];
        int s1 = (int)srcs[p + 1];
        int s2 = (int)srcs[p + 2];
        int s3 = (int)srcs[p + 3];
        int s4 = (int)srcs[p + 4];
        int s5 = (int)srcs[p + 5];
        int s6 = (int)srcs[p + 6];
        int s7 = (int)srcs[p + 7];
        a0 += (float)t[(size_t)s0 * 64 + lane];
        a1 += (float)t[(size_t)s1 * 64 + lane];
        a2 += (float)t[(size_t)s2 * 64 + lane];
        a3 += (float)t[(size_t)s3 * 64 + lane];
        a4 += (float)t[(size_t)s4 * 64 + lane];
        a5 += (float)t[(size_t)s5 * 64 + lane];
        a6 += (float)t[(size_t)s6 * 64 + lane];
        a7 += (float)t[(size_t)s7 * 64 + lane];
    }
    for (; p < end; ++p) a0 += (float)t[(size_t)(int)srcs[p] * 64 + lane];
    float z = a0 + ((a1 + a2) + (a3 + a4)) + ((a5 + a6) + a7) + bias[lane];
    out[(size_t)node * 64 + lane] = 1.f / (1.f + __expf(-z));
}

// ---------------- MFMA MLP: out = relu(relu(in @ Wa + ba) @ Wb + bb) ----------------
// bf16 hi/lo split, 3 MFMA terms. 64 rows/block, 4 waves, wave owns 16 rows.
// R11 structure; cvt8 now uses native __bf16 casts (compiler emits packed cvt),
// ~3 VALU ops/element vs ~10 for the integer-RNE path.

__device__ __forceinline__ void cvt8(const float4 p, const float4 q,
                                     bf16x8& hi, bf16x8& lo) {
    short hb, lb;
    split_bf16(p.x, hb, lb); hi[0] = hb; lo[0] = lb;
    split_bf16(p.y, hb, lb); hi[1] = hb; lo[1] = lb;
    split_bf16(p.z, hb, lb); hi[2] = hb; lo[2] = lb;
    split_bf16(p.w, hb, lb); hi[3] = hb; lo[3] = lb;
    split_bf16(q.x, hb, lb); hi[4] = hb; lo[4] = lb;
    split_bf16(q.y, hb, lb); hi[5] = hb; lo[5] = lb;
    split_bf16(q.z, hb, lb); hi[6] = hb; lo[6] = lb;
    split_bf16(q.w, hb, lb); hi[7] = hb; lo[7] = lb;
}

template <bool WRITE_GLOBAL>
__device__ __forceinline__ void gemm_phase_mfma(float* __restrict__ myrows,
                                                const short* __restrict__ wp,
                                                const float* __restrict__ bias,
                                                int arow, int agrp,
                                                int l, float* __restrict__ gout,
                                                int row_base, int N) {
    f32x4 acc[8];
#pragma unroll
    for (int ct = 0; ct < 8; ++ct) acc[ct] = (f32x4){0.f, 0.f, 0.f, 0.f};

    const short* wlo = wp + 16384;
#pragma unroll
    for (int kc = 0; kc < 4; ++kc) {
        const float* ap = &myrows[arow * 132 + kc * 32 + agrp * 8];
        float4 p = *(const float4*)ap;
        float4 q = *(const float4*)(ap + 4);
        bf16x8 ahi, alo;
        cvt8(p, q, ahi, alo);
#pragma unroll
        for (int ct = 0; ct < 8; ++ct) {
            const int off = ((ct * 4 + kc) << 9) + (l << 3);
            bf16x8 bhi = *(const bf16x8*)(wp + off);
            bf16x8 blo = *(const bf16x8*)(wlo + off);
            acc[ct] = __builtin_amdgcn_mfma_f32_16x16x32_bf16(ahi, bhi, acc[ct], 0, 0, 0);
            acc[ct] = __builtin_amdgcn_mfma_f32_16x16x32_bf16(alo, bhi, acc[ct], 0, 0, 0);
            acc[ct] = __builtin_amdgcn_mfma_f32_16x16x32_bf16(ahi, blo, acc[ct], 0, 0, 0);
        }
    }

#pragma unroll
    for (int ct = 0; ct < 8; ++ct) {
        float bv = bias[ct * 16 + arow];  // D col = ct*16 + (lane&15)
#pragma unroll
        for (int r = 0; r < 4; ++r) {
            float v = fmaxf(acc[ct][r] + bv, 0.f);  // D row = agrp*4 + r
            if (WRITE_GLOBAL) {
                int row = row_base + agrp * 4 + r;
                if (row < N) gout[(size_t)row * 128 + ct * 16 + arow] = v;
            } else {
                myrows[(agrp * 4 + r) * 132 + ct * 16 + arow] = v;
            }
        }
    }
}

__global__ __launch_bounds__(256, 4) void mlp2_mfma_kernel(
    const float* __restrict__ in,
    const short* __restrict__ wpa, const float* __restrict__ ba,
    const short* __restrict__ wpb, const float* __restrict__ bb,
    float* __restrict__ out, int N) {
    __shared__ float sh[64 * 132];
    const int tid = threadIdx.x;
    const int wave = tid >> 6;
    const int l = tid & 63;
    const int arow = l & 15;
    const int agrp = l >> 4;
    const int row0 = blockIdx.x * 64;

    const float4* in4 = (const float4*)in;
#pragma unroll
    for (int it = 0; it < 8; ++it) {
        int i = tid + it * 256;
        int r = i >> 5, c = i & 31;
        int row = row0 + r;
        float4 z = {0.f, 0.f, 0.f, 0.f};
        float4 v = (row < N) ? in4[(size_t)row * 32 + c] : z;
        *(float4*)&sh[r * 132 + c * 4] = v;
    }
    __syncthreads();

    float* myrows = &sh[wave * 16 * 132];
    gemm_phase_mfma<false>(myrows, wpa, ba, arow, agrp, l, nullptr, 0, N);
    __syncthreads();
    gemm_phase_mfma<true>(myrows, wpb, bb, arow, agrp, l, out, row0 + wave * 16, N);
}

// ---------------- last layer: t = in @ W (J=64), emit fp16 ----------------

__global__ __launch_bounds__(256, 6) void gemm64_kernel(const float* __restrict__ in,
                                                        const float* __restrict__ W,
                                                        _Float16* __restrict__ out, int N) {
    constexpr int TX = 16, RPT = 2;
    __shared__ float4 sh[32 * 32];

    int tid = threadIdx.x;
    int tx = tid % TX;
    int ty = tid / TX;
    int row0 = blockIdx.x * 32;

    const float4* in4 = (const float4*)in;
    for (int i = tid; i < 32 * 32; i += 256) {
        int r = i >> 5, c = i & 31;
        int row = row0 + r;
        float4 z = {0.f, 0.f, 0.f, 0.f};
        sh[i] = (row < N) ? in4[(size_t)row * 32 + c] : z;
    }
    __syncthreads();

    const float4* W4 = (const float4*)W;
    float acc[RPT][4];
#pragma unroll
    for (int r = 0; r < RPT; ++r)
#pragma unroll
        for (int c = 0; c < 4; ++c) acc[r][c] = 0.f;

#pragma unroll 4
    for (int kk = 0; kk < 128; kk += 4) {
        float4 w0 = W4[(kk + 0) * TX + tx];
        float4 w1 = W4[(kk + 1) * TX + tx];
        float4 w2 = W4[(kk + 2) * TX + tx];
        float4 w3 = W4[(kk + 3) * TX + tx];
#pragma unroll
        for (int r = 0; r < RPT; ++r) {
            float4 hv = sh[(ty * RPT + r) * 32 + (kk >> 2)];
            acc[r][0] += hv.x * w0.x + hv.y * w1.x + hv.z * w2.x + hv.w * w3.x;
            acc[r][1] += hv.x * w0.y + hv.y * w1.y + hv.z * w2.y + hv.w * w3.y;
            acc[r][2] += hv.x * w0.z + hv.y * w1.z + hv.z * w2.z + hv.w * w3.z;
            acc[r][3] += hv.x * w0.w + hv.y * w1.w + hv.z * w2.w + hv.w * w3.w;
        }
    }

#pragma unroll
    for (int r = 0; r < RPT; ++r) {
        int row = row0 + ty * RPT + r;
        if (row < N) {
            f16x4 v;
            v[0] = (_Float16)acc[r][0];
            v[1] = (_Float16)acc[r][1];
            v[2] = (_Float16)acc[r][2];
            v[3] = (_Float16)acc[r][3];
            *(f16x4*)&out[(size_t)row * 64 + tx * 4] = v;
        }
    }
}

// ---------------- orchestration ----------------

template <typename IT>
static void run_graph(const float* x, const int* ei, int N, int E,
                      const float* w0a, const float* b0a, const float* w0b, const float* b0b,
                      const float* wma, const float* bma, const float* wmb, const float* bmb,
                      const float* wl, const float* bl,
                      float* A, float* B, int* deg, int* rowp, int* cur, int* bsum,
                      IT* srcs, short* wpack, float* out, hipStream_t stream) {
    const int NB = (N + 255) / 256;
    dim3 blk(256);

    pack_w_kernel<<<(10 * 16384 + 255) / 256, blk, 0, stream>>>(w0a, w0b, wma, wmb, wpack);

    hipMemsetAsync(deg, 0, (size_t)N * sizeof(int), stream);
    hist_kernel<<<(E + 255) / 256, blk, 0, stream>>>(ei, E, deg);
    scan1_kernel<<<NB, blk, 0, stream>>>(deg, rowp, bsum, N);
    scan2_kernel<<<1, blk, 0, stream>>>(bsum, NB);
    scan3_kernel<<<NB, blk, 0, stream>>>(rowp, bsum, cur, N, E);
    scatter_kernel<IT><<<(E + 255) / 256, blk, 0, stream>>>(ei, E, cur, srcs);

    const int agg_grid  = (N + 7) / 8;
    const int aggo_grid = (N + 3) / 4;
    const int m64_grid  = (N + 63) / 64;
    const int g32_grid  = (N + 31) / 32;

    // layer 0
    agg_kernel<IT><<<agg_grid, blk, 0, stream>>>(x, rowp, srcs, A, N);
    mlp2_mfma_kernel<<<m64_grid, blk, 0, stream>>>(A, wpack + 0, b0a,
                                                   wpack + 32768, b0b, B, N);

    // middle layers 1..4
    float* h = B;
    float* o = A;
    for (int l = 0; l < 4; ++l) {
        const short* wpa = wpack + (size_t)(2 + l) * 32768;
        const short* wpb = wpack + (size_t)(6 + l) * 32768;
        const float* ba = bma + (size_t)l * HDIM;
        const float* bb = bmb + (size_t)l * HDIM;
        agg_kernel<IT><<<agg_grid, blk, 0, stream>>>(h, rowp, srcs, o, N);
        mlp2_mfma_kernel<<<m64_grid, blk, 0, stream>>>(o, wpa, ba, wpb, bb, h, N);
    }

    // last layer: t = h @ wl (fp16) ; out = sigmoid(t + S t + bl)
    _Float16* t16 = (_Float16*)o;
    gemm64_kernel<<<g32_grid, blk, 0, stream>>>(h, wl, t16, N);
    agg_out_kernel<IT><<<aggo_grid, blk, 0, stream>>>(t16, rowp, srcs, bl, out, N);
}

extern "C" void kernel_launch(void* const* d_in, const int* in_sizes, int n_in,
                              void* d_out, int out_size, void* d_ws, size_t ws_size,
                              hipStream_t stream) {
    const float* x   = (const float*)d_in[0];
    const int*   ei  = (const int*)d_in[1];
    const float* w0a = (const float*)d_in[2];
    const float* b0a = (const float*)d_in[3];
    const float* w0b = (const float*)d_in[4];
    const float* b0b = (const float*)d_in[5];
    const float* wma = (const float*)d_in[6];
    const float* bma = (const float*)d_in[7];
    const float* wmb = (const float*)d_in[8];
    const float* bmb = (const float*)d_in[9];
    const float* wl  = (const float*)d_in[10];
    const float* bl  = (const float*)d_in[11];

    const int N = in_sizes[0] / HDIM;
    const int E = in_sizes[1] / 2;

    // workspace layout
    float* A = (float*)d_ws;
    float* B = A + (size_t)N * HDIM;
    int* deg  = (int*)(B + (size_t)N * HDIM);
    int* rowp = deg + N;
    int* cur  = rowp + N + 1;
    int* bsum = cur + N;
    int* srcs = bsum + 256;              // E ints of space (ushort uses half)
    short* wpack = (short*)(srcs + E);   // 10 * 32768 shorts = 640 KiB

    if (N <= 65535) {
        run_graph<unsigned short>(x, ei, N, E, w0a, b0a, w0b, b0b, wma, bma, wmb, bmb,
                                  wl, bl, A, B, deg, rowp, cur, bsum,
                                  (unsigned short*)srcs, wpack, (float*)d_out, stream);
    } else {
        run_graph<int>(x, ei, N, E, w0a, b0a, w0b, b0b, wma, bma, wmb, bmb,
                       wl, bl, A, B, deg, rowp, cur, bsum,
                       srcs, wpack, (float*)d_out, stream);
    }
}